// Round 1
// baseline (179.511 us; speedup 1.0000x reference)
//
#include <hip/hip_runtime.h>

// Problem constants
#define T_STEPS 100
#define BATCH   32
#define NIN     1024
#define NOUT    512

#define LR_LTP   (1e-4f)
#define LR_LTD   (-1e-4f)
#define INV_B    (1.0f / 32.0f)

// K dimension of the two accumulated outer-product GEMMs
#define KTOT   (T_STEPS * BATCH)   // 3200
#define KS     4                   // K-split factor
#define KCHUNK (KTOT / KS)         // 800
#define BK     32

// Output layout (floats): [delta_w | pre_tr | post_tr]
#define OFF_PRE  (NOUT * NIN)                  // 524288
#define OFF_POST (OFF_PRE + BATCH * NIN)       // 557056

// Workspace layout (floats):
//   ws_pre  : [T, B, NIN]   traces           = 3,276,800
//   ws_post : [T, B, NOUT]  traces           = 1,638,400
//   Spart   : [KS][2][NOUT][NIN] partials    = 4,194,304
#define WS_PRE_OFF  0
#define WS_POST_OFF (T_STEPS * BATCH * NIN)                 // 3276800
#define WS_S_OFF    (WS_POST_OFF + T_STEPS * BATCH * NOUT)  // 4915200

// ---------------------------------------------------------------------------
// Kernel 1: trace recurrence. One thread per (b, channel). Writes all
// intermediate traces to ws and final traces to out.
// ---------------------------------------------------------------------------
__global__ __launch_bounds__(256) void stdp_traces(
    const float* __restrict__ pre_s,    // [T,B,NIN]
    const float* __restrict__ post_s,   // [T,B,NOUT]
    const float* __restrict__ pre_tr0,  // [B,NIN]
    const float* __restrict__ post_tr0, // [B,NOUT]
    float* __restrict__ ws_pre,         // [T,B,NIN]
    float* __restrict__ ws_post,        // [T,B,NOUT]
    float* __restrict__ out)
{
    const float decay = expf(-1.0f / 20.0f);  // TAU_PRE == TAU_POST
    int tid = blockIdx.x * blockDim.x + threadIdx.x;
    if (tid < BATCH * NIN) {
        float tr = pre_tr0[tid];
        #pragma unroll 4
        for (int t = 0; t < T_STEPS; ++t) {
            tr = tr * decay + pre_s[t * (BATCH * NIN) + tid];
            ws_pre[t * (BATCH * NIN) + tid] = tr;
        }
        out[OFF_PRE + tid] = tr;
    } else {
        int id = tid - BATCH * NIN;
        if (id < BATCH * NOUT) {
            float tr = post_tr0[id];
            #pragma unroll 4
            for (int t = 0; t < T_STEPS; ++t) {
                tr = tr * decay + post_s[t * (BATCH * NOUT) + id];
                ws_post[t * (BATCH * NOUT) + id] = tr;
            }
            out[OFF_POST + id] = tr;
        }
    }
}

// ---------------------------------------------------------------------------
// Kernel 2: dual GEMM. C_ltp[o,i] = sum_k post_s[k,o]*pre_tr[k,i]
//                      C_ltd[o,i] = sum_k post_tr[k,o]*pre_s[k,i]
// 64x64 output tile per block, BK=32, 4x4 micro-tile, K-split over blockIdx.z.
// ---------------------------------------------------------------------------
__global__ __launch_bounds__(256) void stdp_gemm(
    const float* __restrict__ pre_s,    // [KTOT, NIN]
    const float* __restrict__ post_s,   // [KTOT, NOUT]
    const float* __restrict__ ws_pre,   // [KTOT, NIN]
    const float* __restrict__ ws_post,  // [KTOT, NOUT]
    float* __restrict__ Spart)          // [KS][2][NOUT][NIN]
{
    __shared__ float sPostS[BK][64];
    __shared__ float sPostT[BK][64];
    __shared__ float sPreT[BK][64];
    __shared__ float sPreS[BK][64];

    const int tid = threadIdx.x;
    const int tx = tid & 15;        // 0..15 -> i within tile (x4)
    const int ty = tid >> 4;        // 0..15 -> o within tile (x4)
    const int i0 = blockIdx.x * 64;
    const int o0 = blockIdx.y * 64;
    const int k0 = blockIdx.z * KCHUNK;

    float accP[4][4] = {};
    float accD[4][4] = {};

    for (int kb = 0; kb < KCHUNK; kb += BK) {
        const int kbase = k0 + kb;
        // Stage 4 tiles of [32][64] floats; 512 float4 per tile, 2 per thread.
        #pragma unroll
        for (int r = 0; r < 2; ++r) {
            const int idx = tid + r * 256;      // 0..511
            const int row = idx >> 4;           // 0..31
            const int c4  = (idx & 15) * 4;     // 0,4,..,60
            const float4 a = *(const float4*)&post_s [(size_t)(kbase + row) * NOUT + o0 + c4];
            const float4 b = *(const float4*)&ws_post[(size_t)(kbase + row) * NOUT + o0 + c4];
            const float4 c = *(const float4*)&ws_pre [(size_t)(kbase + row) * NIN  + i0 + c4];
            const float4 d = *(const float4*)&pre_s  [(size_t)(kbase + row) * NIN  + i0 + c4];
            *(float4*)&sPostS[row][c4] = a;
            *(float4*)&sPostT[row][c4] = b;
            *(float4*)&sPreT [row][c4] = c;
            *(float4*)&sPreS [row][c4] = d;
        }
        __syncthreads();

        #pragma unroll
        for (int k = 0; k < BK; ++k) {
            float aP[4], aD[4], bP[4], bD[4];
            *(float4*)aP = *(const float4*)&sPostS[k][ty * 4];
            *(float4*)aD = *(const float4*)&sPostT[k][ty * 4];
            *(float4*)bP = *(const float4*)&sPreT [k][tx * 4];
            *(float4*)bD = *(const float4*)&sPreS [k][tx * 4];
            #pragma unroll
            for (int m = 0; m < 4; ++m)
                #pragma unroll
                for (int n = 0; n < 4; ++n) {
                    accP[m][n] += aP[m] * bP[n];
                    accD[m][n] += aD[m] * bD[n];
                }
        }
        __syncthreads();
    }

    float* Sp = Spart + ((size_t)blockIdx.z * 2 + 0) * (NOUT * NIN);
    float* Sd = Spart + ((size_t)blockIdx.z * 2 + 1) * (NOUT * NIN);
    #pragma unroll
    for (int m = 0; m < 4; ++m) {
        const int o = o0 + ty * 4 + m;
        *(float4*)&Sp[(size_t)o * NIN + i0 + tx * 4] = *(float4*)accP[m];
        *(float4*)&Sd[(size_t)o * NIN + i0 + tx * 4] = *(float4*)accD[m];
    }
}

// ---------------------------------------------------------------------------
// Kernel 3: finalize. dw = LR_LTP*(1-w)*S_ltp/B + LR_LTD*w*S_ltd/B
// ---------------------------------------------------------------------------
__global__ __launch_bounds__(256) void stdp_finalize(
    const float* __restrict__ w,
    const float* __restrict__ Spart,
    float* __restrict__ out)
{
    const int j = blockIdx.x * blockDim.x + threadIdx.x;   // float4 index
    const int MN4 = (NOUT * NIN) / 4;
    if (j >= MN4) return;

    const float4 wv = ((const float4*)w)[j];
    float4 sp = make_float4(0.f, 0.f, 0.f, 0.f);
    float4 sd = make_float4(0.f, 0.f, 0.f, 0.f);
    #pragma unroll
    for (int ks = 0; ks < KS; ++ks) {
        const float4 p = ((const float4*)(Spart + ((size_t)ks * 2 + 0) * (NOUT * NIN)))[j];
        const float4 d = ((const float4*)(Spart + ((size_t)ks * 2 + 1) * (NOUT * NIN)))[j];
        sp.x += p.x; sp.y += p.y; sp.z += p.z; sp.w += p.w;
        sd.x += d.x; sd.y += d.y; sd.z += d.z; sd.w += d.w;
    }
    float4 o;
    o.x = LR_LTP * (1.0f - wv.x) * sp.x * INV_B + LR_LTD * wv.x * sd.x * INV_B;
    o.y = LR_LTP * (1.0f - wv.y) * sp.y * INV_B + LR_LTD * wv.y * sd.y * INV_B;
    o.z = LR_LTP * (1.0f - wv.z) * sp.z * INV_B + LR_LTD * wv.z * sd.z * INV_B;
    o.w = LR_LTP * (1.0f - wv.w) * sp.w * INV_B + LR_LTD * wv.w * sd.w * INV_B;
    ((float4*)out)[j] = o;
}

extern "C" void kernel_launch(void* const* d_in, const int* in_sizes, int n_in,
                              void* d_out, int out_size, void* d_ws, size_t ws_size,
                              hipStream_t stream) {
    const float* weight   = (const float*)d_in[0];
    const float* pre_s    = (const float*)d_in[1];
    const float* post_s   = (const float*)d_in[2];
    const float* pre_tr0  = (const float*)d_in[3];
    const float* post_tr0 = (const float*)d_in[4];
    float* out = (float*)d_out;

    float* ws      = (float*)d_ws;
    float* ws_pre  = ws + WS_PRE_OFF;
    float* ws_post = ws + WS_POST_OFF;
    float* Spart   = ws + WS_S_OFF;

    // 1) traces: (B*NIN + B*NOUT) = 49152 threads
    stdp_traces<<<dim3((BATCH * NIN + BATCH * NOUT) / 256), dim3(256), 0, stream>>>(
        pre_s, post_s, pre_tr0, post_tr0, ws_pre, ws_post, out);

    // 2) dual GEMM: 16 x 8 x KS blocks
    stdp_gemm<<<dim3(NIN / 64, NOUT / 64, KS), dim3(256), 0, stream>>>(
        pre_s, post_s, ws_pre, ws_post, Spart);

    // 3) finalize
    stdp_finalize<<<dim3((NOUT * NIN / 4) / 256), dim3(256), 0, stream>>>(
        weight, Spart, out);
}

// Round 2
// 115.412 us; speedup vs baseline: 1.5554x; 1.5554x over previous
//
#include <hip/hip_runtime.h>

typedef unsigned short ushort;
typedef __attribute__((ext_vector_type(8))) short short8;
typedef __attribute__((ext_vector_type(8))) ushort ushort8;
typedef __attribute__((ext_vector_type(4))) float floatx4;

// Problem constants
#define T_STEPS 100
#define BATCH   32
#define NIN     1024
#define NOUT    512
#define KTOT    (T_STEPS * BATCH)      // 3200
#define KBYTES  (KTOT * 2)             // 6400 bytes per transposed row

#define LR_LTP  (1e-4f)
#define LR_LTD  (-1e-4f)
#define INV_B   (1.0f / 32.0f)
#define DECAY   0.951229424500714f     // float(exp(-1/20))

// Output layout (floats): [delta_w | pre_tr_final | post_tr_final]
#define OFF_PRE  (NOUT * NIN)
#define OFF_POST (OFF_PRE + BATCH * NIN)

// Workspace layout (ushort elements unless noted):
//   ws_pre16  [KTOT][NIN]   bf16 traces (k-major)    3,276,800
//   ws_post16 [KTOT][NOUT]                            1,638,400
//   pre_s_t   [NIN][KTOT]   bf16 transposed spikes    3,276,800
//   post_s_t  [NOUT][KTOT]                            1,638,400
//   pre_tr_t  [NIN][KTOT]   bf16 transposed traces    3,276,800
//   post_tr_t [NOUT][KTOT]                            1,638,400
//   Spart     [2*KS][NOUT][NIN] fp32 partials
#define U_WSPRE   0
#define U_WSPOST  (U_WSPRE + KTOT * NIN)
#define U_PRST    (U_WSPOST + KTOT * NOUT)
#define U_POST_ST (U_PRST + NIN * KTOT)
#define U_PRTT    (U_POST_ST + NOUT * KTOT)
#define U_POTT    (U_PRTT + NIN * KTOT)
#define U_END     (U_POTT + NOUT * KTOT)   // 14,745,600 ushort = 29,491,200 B

static __device__ __forceinline__ ushort f2bf(float f) {
    union { float f; unsigned int u; } v; v.f = f;
    unsigned int r = (v.u + 0x7FFFu + ((v.u >> 16) & 1u)) >> 16;   // RNE
    return (ushort)r;
}

// ---------------------------------------------------------------------------
// Kernel 1: trace recurrence. Batched loads (10 in flight) for ILP.
// Writes bf16 k-major traces to ws, fp32 final traces to out.
// ---------------------------------------------------------------------------
__global__ __launch_bounds__(256) void stdp_traces(
    const float* __restrict__ pre_s,    // [T,B,NIN]  = [KTOT, NIN] k-major rows
    const float* __restrict__ post_s,   // [T,B,NOUT]
    const float* __restrict__ pre_tr0,  // [B,NIN]
    const float* __restrict__ post_tr0, // [B,NOUT]
    ushort* __restrict__ ws_pre16,      // [KTOT, NIN] bf16
    ushort* __restrict__ ws_post16,     // [KTOT, NOUT]
    float* __restrict__ out)
{
    const int tid = blockIdx.x * blockDim.x + threadIdx.x;
    if (tid < BATCH * NIN) {
        float tr = pre_tr0[tid];
        for (int t0 = 0; t0 < T_STEPS; t0 += 10) {
            float s[10];
            #pragma unroll
            for (int j = 0; j < 10; ++j)
                s[j] = pre_s[(size_t)(t0 + j) * (BATCH * NIN) + tid];
            #pragma unroll
            for (int j = 0; j < 10; ++j) {
                tr = tr * DECAY + s[j];
                ws_pre16[(size_t)(t0 + j) * (BATCH * NIN) + tid] = f2bf(tr);
            }
        }
        out[OFF_PRE + tid] = tr;
    } else {
        const int id = tid - BATCH * NIN;
        if (id < BATCH * NOUT) {
            float tr = post_tr0[id];
            for (int t0 = 0; t0 < T_STEPS; t0 += 10) {
                float s[10];
                #pragma unroll
                for (int j = 0; j < 10; ++j)
                    s[j] = post_s[(size_t)(t0 + j) * (BATCH * NOUT) + id];
                #pragma unroll
                for (int j = 0; j < 10; ++j) {
                    tr = tr * DECAY + s[j];
                    ws_post16[(size_t)(t0 + j) * (BATCH * NOUT) + id] = f2bf(tr);
                }
            }
            out[OFF_POST + id] = tr;
        }
    }
}

// ---------------------------------------------------------------------------
// Kernel 2: transpose all four operands to [N][K] bf16 row-major.
// 64x64 tiles via LDS. grid = (KTOT/64=50, 48); y selects region.
//   y 0..15  : pre_s   (fp32 src) -> pre_s_t
//   y 16..23 : post_s  (fp32 src) -> post_s_t
//   y 24..39 : ws_pre16 (bf16 src)-> pre_tr_t
//   y 40..47 : ws_post16         -> post_tr_t
// ---------------------------------------------------------------------------
__global__ __launch_bounds__(256) void stdp_transpose(
    const float* __restrict__ pre_s, const float* __restrict__ post_s,
    const ushort* __restrict__ ws_pre16, const ushort* __restrict__ ws_post16,
    ushort* __restrict__ pre_s_t, ushort* __restrict__ post_s_t,
    ushort* __restrict__ pre_tr_t, ushort* __restrict__ post_tr_t)
{
    __shared__ ushort tile[64][72];   // row stride 144 B (16B multiple)

    const int y = blockIdx.y;
    const float* srcF = nullptr;
    const ushort* srcH = nullptr;
    ushort* dst; int ncols, n0;
    if (y < 16)       { srcF = pre_s;     dst = pre_s_t;  ncols = NIN;  n0 = y * 64; }
    else if (y < 24)  { srcF = post_s;    dst = post_s_t; ncols = NOUT; n0 = (y - 16) * 64; }
    else if (y < 40)  { srcH = ws_pre16;  dst = pre_tr_t; ncols = NIN;  n0 = (y - 24) * 64; }
    else              { srcH = ws_post16; dst = post_tr_t; ncols = NOUT; n0 = (y - 40) * 64; }

    const int k0 = blockIdx.x * 64;
    const int r  = threadIdx.x >> 2;     // 0..63 (row within tile)
    const int cq = threadIdx.x & 3;      // 0..3  (16-col chunk)

    if (srcF) {
        const float* s = srcF + (size_t)(k0 + r) * ncols + n0 + cq * 16;
        ushort tmp[16];
        #pragma unroll
        for (int v = 0; v < 4; ++v) {
            const float4 f = ((const float4*)s)[v];
            tmp[v * 4 + 0] = f2bf(f.x); tmp[v * 4 + 1] = f2bf(f.y);
            tmp[v * 4 + 2] = f2bf(f.z); tmp[v * 4 + 3] = f2bf(f.w);
        }
        *(ushort8*)&tile[r][cq * 16]     = *(const ushort8*)&tmp[0];
        *(ushort8*)&tile[r][cq * 16 + 8] = *(const ushort8*)&tmp[8];
    } else {
        const ushort* s = srcH + (size_t)(k0 + r) * ncols + n0 + cq * 16;
        *(ushort8*)&tile[r][cq * 16]     = ((const ushort8*)s)[0];
        *(ushort8*)&tile[r][cq * 16 + 8] = ((const ushort8*)s)[1];
    }
    __syncthreads();

    // write out: local col r becomes output row n0+r; k chunk cq*16
    union { ushort u[16]; ushort8 v[2]; } o;
    #pragma unroll
    for (int j = 0; j < 16; ++j) o.u[j] = tile[cq * 16 + j][r];
    ushort* d = dst + (size_t)(n0 + r) * KTOT + k0 + cq * 16;
    ((ushort8*)d)[0] = o.v[0];
    ((ushort8*)d)[1] = o.v[1];
}

// ---------------------------------------------------------------------------
// Kernel 3: dual bf16 MFMA GEMM (m97 structure).
// C[o,i] = sum_k A[o,k]*B[i,k];  A/B row-major [M|N][KTOT] bf16.
// 128x128 tile, BK=32, 4 waves in 2x2, 16x16x32 MFMA, global_load_lds w=16.
// blockIdx.z: bit0 = gemm id (0: LTP post_s*pre_tr, 1: LTD post_tr*pre_s),
//             z>>1 = K-split chunk. Writes fp32 partials to Spart[z].
// ---------------------------------------------------------------------------
__global__ __launch_bounds__(256) void stdp_mfma_gemm(
    const ushort* __restrict__ post_s_t, const ushort* __restrict__ pre_tr_t,
    const ushort* __restrict__ post_tr_t, const ushort* __restrict__ pre_s_t,
    float* __restrict__ Spart, int kchunk)
{
    __shared__ ushort As[128 * 32];   // [row][k] 64 B rows, 8 KB
    __shared__ ushort Bs[128 * 32];

    const int z = blockIdx.z;
    const ushort* Ag = (z & 1) ? post_tr_t : post_s_t;   // M = NOUT rows
    const ushort* Bg = (z & 1) ? pre_s_t   : pre_tr_t;   // N = NIN rows
    const int i0 = blockIdx.x * 128;
    const int o0 = blockIdx.y * 128;
    const int k0 = (z >> 1) * kchunk;

    const int tid  = threadIdx.x;
    const int w    = tid >> 6;
    const int lane = tid & 63;
    const int quad = lane >> 4;
    const int l16  = lane & 15;
    const int wm   = w & 1;       // wave quadrant row
    const int wn   = w >> 1;      // wave quadrant col

    floatx4 acc[4][4];
    const floatx4 zero4 = {0.f, 0.f, 0.f, 0.f};
    #pragma unroll
    for (int mt = 0; mt < 4; ++mt)
        #pragma unroll
        for (int nt = 0; nt < 4; ++nt) acc[mt][nt] = zero4;

    for (int kb = k0; kb < k0 + kchunk; kb += 32) {
        // stage A,B tiles: each wave stages 2 KB of each via 2 instrs
        #pragma unroll
        for (int q = 0; q < 2; ++q) {
            const int c   = w * 128 + q * 64 + lane;   // 16B chunk id 0..511
            const int row = c >> 2;
            const int kob = (c & 3) * 16;              // byte offset in row
            const char* ga = (const char*)Ag + (size_t)(o0 + row) * KBYTES + kb * 2 + kob;
            const char* gb = (const char*)Bg + (size_t)(i0 + row) * KBYTES + kb * 2 + kob;
            __builtin_amdgcn_global_load_lds(
                (const __attribute__((address_space(1))) void*)ga,
                (__attribute__((address_space(3))) void*)((char*)As + w * 2048 + q * 1024),
                16, 0, 0);
            __builtin_amdgcn_global_load_lds(
                (const __attribute__((address_space(1))) void*)gb,
                (__attribute__((address_space(3))) void*)((char*)Bs + w * 2048 + q * 1024),
                16, 0, 0);
        }
        __syncthreads();

        short8 a[4], b[4];
        #pragma unroll
        for (int mt = 0; mt < 4; ++mt)
            a[mt] = *(const short8*)&As[(wm * 64 + mt * 16 + l16) * 32 + quad * 8];
        #pragma unroll
        for (int nt = 0; nt < 4; ++nt)
            b[nt] = *(const short8*)&Bs[(wn * 64 + nt * 16 + l16) * 32 + quad * 8];
        #pragma unroll
        for (int mt = 0; mt < 4; ++mt)
            #pragma unroll
            for (int nt = 0; nt < 4; ++nt)
                acc[mt][nt] = __builtin_amdgcn_mfma_f32_16x16x32_bf16(
                    a[mt], b[nt], acc[mt][nt], 0, 0, 0);
        __syncthreads();
    }

    // epilogue: C/D layout col = lane&15 (n/i), row = quad*4+reg (m/o)
    float* S = Spart + (size_t)z * (NOUT * NIN);
    const int r0 = quad * 4;
    #pragma unroll
    for (int mt = 0; mt < 4; ++mt) {
        const int obase = o0 + wm * 64 + mt * 16 + r0;
        #pragma unroll
        for (int nt = 0; nt < 4; ++nt) {
            const int i = i0 + wn * 64 + nt * 16 + l16;
            #pragma unroll
            for (int r = 0; r < 4; ++r)
                S[(size_t)(obase + r) * NIN + i] = acc[mt][nt][r];
        }
    }
}

// ---------------------------------------------------------------------------
// Kernel 4: finalize. dw = LR_LTP*(1-w)*S_ltp/B + LR_LTD*w*S_ltd/B
// Spart slabs: even = LTP partial, odd = LTD partial.
// ---------------------------------------------------------------------------
__global__ __launch_bounds__(256) void stdp_finalize(
    const float* __restrict__ w,
    const float* __restrict__ Spart,
    float* __restrict__ out, int nslab)
{
    const int j = blockIdx.x * blockDim.x + threadIdx.x;   // float4 index
    const float4 wv = ((const float4*)w)[j];
    float4 sp = make_float4(0.f, 0.f, 0.f, 0.f);
    float4 sd = make_float4(0.f, 0.f, 0.f, 0.f);
    for (int s = 0; s < nslab; s += 2) {
        const float4 p = ((const float4*)(Spart + (size_t)s       * (NOUT * NIN)))[j];
        const float4 d = ((const float4*)(Spart + (size_t)(s + 1) * (NOUT * NIN)))[j];
        sp.x += p.x; sp.y += p.y; sp.z += p.z; sp.w += p.w;
        sd.x += d.x; sd.y += d.y; sd.z += d.z; sd.w += d.w;
    }
    float4 o;
    o.x = LR_LTP * (1.0f - wv.x) * sp.x * INV_B + LR_LTD * wv.x * sd.x * INV_B;
    o.y = LR_LTP * (1.0f - wv.y) * sp.y * INV_B + LR_LTD * wv.y * sd.y * INV_B;
    o.z = LR_LTP * (1.0f - wv.z) * sp.z * INV_B + LR_LTD * wv.z * sd.z * INV_B;
    o.w = LR_LTP * (1.0f - wv.w) * sp.w * INV_B + LR_LTD * wv.w * sd.w * INV_B;
    ((float4*)out)[j] = o;
}

extern "C" void kernel_launch(void* const* d_in, const int* in_sizes, int n_in,
                              void* d_out, int out_size, void* d_ws, size_t ws_size,
                              hipStream_t stream) {
    const float* weight   = (const float*)d_in[0];
    const float* pre_s    = (const float*)d_in[1];
    const float* post_s   = (const float*)d_in[2];
    const float* pre_tr0  = (const float*)d_in[3];
    const float* post_tr0 = (const float*)d_in[4];
    float* out = (float*)d_out;

    ushort* u = (ushort*)d_ws;
    ushort* ws_pre16  = u + U_WSPRE;
    ushort* ws_post16 = u + U_WSPOST;
    ushort* pre_s_t   = u + U_PRST;
    ushort* post_s_t  = u + U_POST_ST;
    ushort* pre_tr_t  = u + U_PRTT;
    ushort* post_tr_t = u + U_POTT;
    float*  Spart     = (float*)((char*)d_ws + (size_t)U_END * 2);

    // pick largest K-split whose partial slabs fit the workspace
    const size_t fixed_bytes = (size_t)U_END * 2;
    const size_t slab_bytes  = (size_t)NOUT * NIN * 4;
    int KS = 1;
    const int cand[5] = {10, 5, 4, 2, 1};
    for (int c = 0; c < 5; ++c) {
        if (fixed_bytes + (size_t)2 * cand[c] * slab_bytes <= ws_size) { KS = cand[c]; break; }
    }
    const int kchunk = KTOT / KS;

    stdp_traces<<<dim3((BATCH * NIN + BATCH * NOUT) / 256), dim3(256), 0, stream>>>(
        pre_s, post_s, pre_tr0, post_tr0, ws_pre16, ws_post16, out);

    stdp_transpose<<<dim3(KTOT / 64, 48), dim3(256), 0, stream>>>(
        pre_s, post_s, ws_pre16, ws_post16, pre_s_t, post_s_t, pre_tr_t, post_tr_t);

    stdp_mfma_gemm<<<dim3(NIN / 128, NOUT / 128, 2 * KS), dim3(256), 0, stream>>>(
        post_s_t, pre_tr_t, post_tr_t, pre_s_t, Spart, kchunk);

    stdp_finalize<<<dim3((NOUT * NIN / 4) / 256), dim3(256), 0, stream>>>(
        weight, Spart, out, 2 * KS);
}